// Round 8
// baseline (190.259 us; speedup 1.0000x reference)
//
#include <hip/hip_runtime.h>
#include <hip/hip_bf16.h>
#include <math.h>

#define NN 200000
#define EE 100000
#define RAWD 172
#define MEMD 100
#define NKT 19            // total k-tiles of 32 (K=608: 472 ih + 8 pad + 100 hh + 28 pad)
#define NCT 19            // col-tiles of 16, contiguous cols 0..303 (300 valid)
#define BM 64             // nodes per block
#define NTHR 512          // 8 waves
#define RSH 328           // X row stride (shorts): 16B-aligned rows, benign banks
#define H1T 10            // half1 k-tiles (k 0..319)
#define H2T 9             // half2 k-tiles (k 320..607)
#define PLNA 308          // main plane row stride (floats)
#define PLNG 104          // gh plane row stride (floats)

typedef __attribute__((ext_vector_type(8))) short bf16x8;
typedef __attribute__((ext_vector_type(4))) float f32x4;

__device__ inline unsigned short f2bf(float v) {
    __hip_bfloat16 h = __float2bfloat16(v);
    unsigned short u; __builtin_memcpy(&u, &h, 2); return u;
}

__device__ inline ushort4 pack4(float4 v) {
    ushort4 r;
    r.x = f2bf(v.x); r.y = f2bf(v.y); r.z = f2bf(v.z); r.w = f2bf(v.w);
    return r;
}

__device__ inline float fsigmoid(float x) { return 1.f / (1.f + __expf(-x)); }
__device__ inline float ftanh(float x) { return 1.f - 2.f / (__expf(2.f * x) + 1.f); }

// Branchless cos: f64 range reduction, f32 polys, quadrant select via bit tricks.
__device__ inline float fast_cos(float x) {
    double xd = (double)x;
    double kd = rint(xd * 0.6366197723675814);      // x * 2/pi
    double r_d = fma(kd, -1.5707963267948966, xd);  // x - k*pi/2
    float r = (float)r_d;
    int ki = (int)kd;
    float s = r * r;
    float c = fmaf(s, fmaf(s, fmaf(s, fmaf(s, 2.4801587e-5f, -1.3888889e-3f),
                                   4.1666668e-2f), -0.5f), 1.0f);
    float sn = r * fmaf(s, fmaf(s, fmaf(s, -1.9841270e-4f, 8.3333338e-3f),
                                -1.6666667e-1f), 1.0f);
    float base = (ki & 1) ? sn : c;
    return ((ki + 1) & 2) ? -base : base;
}

// ---- kernel 1: per-node winner via packed atomicMax key = (t<<32)|(eid+1) ----
__global__ void k_winner(const int* __restrict__ src, const int* __restrict__ dst,
                         const int* __restrict__ t, unsigned long long* __restrict__ keys) {
    int e = blockIdx.x * blockDim.x + threadIdx.x;
    if (e >= 2 * EE) return;
    int re = (e < EE) ? e : e - EE;
    int node = (e < EE) ? src[re] : dst[re];
    unsigned long long key =
        ((unsigned long long)(unsigned)t[re] << 32) | (unsigned)(e + 1);
    atomicMax(&keys[node], key);
}

// ---- kernel 2: decode winner; emit new_last_update (as f32) ----
__global__ void k_nodeinfo(const unsigned long long* __restrict__ keys,
                           const int* __restrict__ src, const int* __restrict__ dst,
                           const int* __restrict__ lu,
                           int* __restrict__ other, int* __restrict__ ew,
                           float* __restrict__ dtv, float* __restrict__ out_lu) {
    int n = blockIdx.x * blockDim.x + threadIdx.x;
    if (n >= NN) return;
    unsigned long long k = keys[n];
    if (k != 0ull) {
        int w = (int)(k & 0xffffffffull) - 1;
        int re = (w < EE) ? w : w - EE;
        other[n] = (w < EE) ? dst[re] : src[re];
        ew[n] = re;
        int tt = (int)(k >> 32);
        dtv[n] = (float)tt - (float)lu[n];
        out_lu[n] = (float)tt;
    } else {
        other[n] = 0;
        ew[n] = -1;
        dtv[n] = 0.f;
        out_lu[n] = (float)lu[n];
    }
}

// ---- kernel 3: pack W into MFMA B-fragment order, bf16 ----
// frag fi = kt*NCT + ct; lane l: out col = ct*16 + (l&15) (contiguous, 300 valid),
// k = kt*32 + (l>>4)*8 + j. K rows: 0..471 w_ih^T; 472..479 0; 480..579 w_hh^T; rest 0.
__global__ void k_pack(const float* __restrict__ w_ih, const float* __restrict__ w_hh,
                       unsigned short* __restrict__ Wb) {
    int id = blockIdx.x * blockDim.x + threadIdx.x;
    if (id >= NKT * NCT * 64) return;
    int lane = id & 63;
    int ct = (id >> 6) % NCT;
    int kt = id / (64 * NCT);
    int col = ct * 16 + (lane & 15);
    int kl = lane >> 4;
    unsigned short o[8];
#pragma unroll
    for (int j = 0; j < 8; ++j) {
        int k = kt * 32 + kl * 8 + j;
        float v = 0.f;
        if (col < 300) {
            if (k < 472) v = w_ih[(size_t)col * 472 + k];
            else if (k >= 480 && k < 580) v = w_hh[(size_t)col * MEMD + (k - 480)];
        }
        o[j] = f2bf(v);
    }
    uint4 v4; __builtin_memcpy(&v4, o, 16);
    *reinterpret_cast<uint4*>(Wb + (size_t)id * 8) = v4;
}

// ---- kernel 4: fused gather + bf16 MFMA dual-GEMM + GRU gates ----
// K split in two single-buffered halves -> LDS ~42KB -> 3 blocks/CU (24 waves).
// 8 waves; wave w owns col-tiles ct = w, w+8, w+16 (<19) for ALL 64 rows.
__global__ __launch_bounds__(NTHR, 4) void k_fused(
    const float* __restrict__ memory, const float* __restrict__ raw_msg,
    const float* __restrict__ time_w, const float* __restrict__ time_b,
    const float* __restrict__ b_ih, const float* __restrict__ b_hh,
    const int* __restrict__ other, const int* __restrict__ ew,
    const float* __restrict__ dtv, const unsigned short* __restrict__ Wb,
    float* __restrict__ out_mem) {
    __shared__ alignas(16) char smem[BM * RSH * 2];   // 41984 B
    unsigned short* Xs = reinterpret_cast<unsigned short*>(smem);
    float* planesA = reinterpret_cast<float*>(smem);                    // [16][PLNA]
    float* planesG = reinterpret_cast<float*>(smem) + 16 * PLNA;        // [16][PLNG]
    __shared__ int s_other[BM];
    __shared__ int s_ew[BM];
    __shared__ float s_dt[BM];

    const int tid = threadIdx.x;
    const int nbase = blockIdx.x * BM;

    if (tid < BM) {
        s_other[tid] = other[nbase + tid];
        s_ew[tid] = ew[nbase + tid];
        s_dt[tid] = dtv[nbase + tid];
    }
    __syncthreads();

    const ushort4 z4 = {0, 0, 0, 0};
    const int w = tid >> 6;
    const int l = tid & 63;
    const int lrow = l & 15, lk = l >> 4;
    const bf16x8* Wbv = reinterpret_cast<const bf16x8*>(Wb);

    f32x4 acc[3][4];           // [owned ct][rowgroup]
    f32x4 acch[4];             // gh-only accumulator (each wave owns <=1 ct>=12)
#pragma unroll
    for (int i = 0; i < 3; ++i)
#pragma unroll
        for (int rg = 0; rg < 4; ++rg) acc[i][rg] = (f32x4){0.f, 0.f, 0.f, 0.f};
#pragma unroll
    for (int rg = 0; rg < 4; ++rg) acch[rg] = (f32x4){0.f, 0.f, 0.f, 0.f};

    const int r10 = blockIdx.x % H1T;
    const int r9 = blockIdx.x % H2T;

    // ---------------- half 1: k in [0,320) ----------------
    // prologue B load for half1 first tile (latency hides under build)
    bf16x8 b[3];
    {
        int kt0 = r10;
#pragma unroll
        for (int i = 0; i < 3; ++i) {
            int ct = w + 8 * i;
            if (ct < NCT) b[i] = Wbv[(kt0 * NCT + ct) * 64 + l];
        }
    }

    // build half1
    // seg other-mem: k [100,200)
    for (int i = tid; i < BM * 25; i += NTHR) {
        int row = i / 25, c = i - row * 25;
        int e = s_ew[row];
        float4 v = *reinterpret_cast<const float4*>(
            memory + (size_t)s_other[row] * MEMD + 4 * c);
        ushort4 h = (e >= 0) ? pack4(v) : z4;
        *reinterpret_cast<ushort4*>(&Xs[row * RSH + 100 + 4 * c]) = h;
    }
    // seg raw part1: cols 0..119 -> k [200,320)
    for (int i = tid; i < BM * 30; i += NTHR) {
        int row = i / 30, c = i - row * 30;
        int e = s_ew[row];
        int eb = e < 0 ? 0 : e;
        float4 v = *reinterpret_cast<const float4*>(
            raw_msg + (size_t)eb * RAWD + 4 * c);
        ushort4 h = (e >= 0) ? pack4(v) : z4;
        *reinterpret_cast<ushort4*>(&Xs[row * RSH + 200 + 4 * c]) = h;
    }
    // seg self-mem masked: k [0,100)
    for (int i = tid; i < BM * 25; i += NTHR) {
        int row = i / 25, c = i - row * 25;
        float4 v = *reinterpret_cast<const float4*>(
            memory + (size_t)(nbase + row) * MEMD + 4 * c);
        ushort4 h = (s_ew[row] >= 0) ? pack4(v) : z4;
        *reinterpret_cast<ushort4*>(&Xs[row * RSH + 4 * c]) = h;
    }
    __syncthreads();

    // MFMA half1 (tiles 0..9, rotated start; no gh tail here)
    for (int idx = 0; idx < H1T; ++idx) {
        int kt = r10 + idx; if (kt >= H1T) kt -= H1T;
        bf16x8 bn[3];
#pragma unroll
        for (int i = 0; i < 3; ++i) bn[i] = b[i];
        if (idx + 1 < H1T) {
            int ktn = r10 + idx + 1; if (ktn >= H1T) ktn -= H1T;
#pragma unroll
            for (int i = 0; i < 3; ++i) {
                int ct = w + 8 * i;
                if (ct < NCT) bn[i] = Wbv[(ktn * NCT + ct) * 64 + l];
            }
        }
        bf16x8 a[4];
#pragma unroll
        for (int rg = 0; rg < 4; ++rg)
            a[rg] = *reinterpret_cast<const bf16x8*>(
                &Xs[(16 * rg + lrow) * RSH + kt * 32 + lk * 8]);
#pragma unroll
        for (int i = 0; i < 3; ++i) {
            int ct = w + 8 * i;
            if (ct < NCT) {
#pragma unroll
                for (int rg = 0; rg < 4; ++rg)
                    acc[i][rg] = __builtin_amdgcn_mfma_f32_16x16x32_bf16(a[rg], b[i], acc[i][rg], 0, 0, 0);
            }
        }
#pragma unroll
        for (int i = 0; i < 3; ++i) b[i] = bn[i];
    }
    __syncthreads();   // Xs about to be overwritten

    // ---------------- half 2: k in [320,608), local = k-320 ----------------
    // prologue B load for half2 first tile (before build: latency hidden)
    {
        int kt0 = 10 + r9;
#pragma unroll
        for (int i = 0; i < 3; ++i) {
            int ct = w + 8 * i;
            if (ct < NCT) b[i] = Wbv[(kt0 * NCT + ct) * 64 + l];
        }
    }

    // build half2
    // raw part2: cols 120..171 -> local [0,52)
    for (int i = tid; i < BM * 13; i += NTHR) {
        int row = i / 13, c = i - row * 13;
        int e = s_ew[row];
        int eb = e < 0 ? 0 : e;
        float4 v = *reinterpret_cast<const float4*>(
            raw_msg + (size_t)eb * RAWD + 120 + 4 * c);
        ushort4 h = (e >= 0) ? pack4(v) : z4;
        *reinterpret_cast<ushort4*>(&Xs[row * RSH + 4 * c]) = h;
    }
    // enc: local [52,152)
    for (int i = tid; i < BM * 25; i += NTHR) {
        int row = i / 25, c = i - row * 25;
        int e = s_ew[row];
        float dt = s_dt[row];
        float4 wv = *reinterpret_cast<const float4*>(time_w + 4 * c);
        float4 bv = *reinterpret_cast<const float4*>(time_b + 4 * c);
        float4 v;
        v.x = fast_cos(__fadd_rn(__fmul_rn(dt, wv.x), bv.x));
        v.y = fast_cos(__fadd_rn(__fmul_rn(dt, wv.y), bv.y));
        v.z = fast_cos(__fadd_rn(__fmul_rn(dt, wv.z), bv.z));
        v.w = fast_cos(__fadd_rn(__fmul_rn(dt, wv.w), bv.w));
        ushort4 h = (e >= 0) ? pack4(v) : z4;
        *reinterpret_cast<ushort4*>(&Xs[row * RSH + 52 + 4 * c]) = h;
    }
    // self-mem unmasked (gh input): local [160,260)
    for (int i = tid; i < BM * 25; i += NTHR) {
        int row = i / 25, c = i - row * 25;
        float4 v = *reinterpret_cast<const float4*>(
            memory + (size_t)(nbase + row) * MEMD + 4 * c);
        *reinterpret_cast<ushort4*>(&Xs[row * RSH + 160 + 4 * c]) = pack4(v);
    }
    // zero pads: local [152,160) (2 chunks) and [260,288) (7 chunks)
    for (int i = tid; i < BM * 9; i += NTHR) {
        int row = i / 9, c = i - row * 9;
        int k = (c < 2) ? (152 + 4 * c) : (260 + 4 * (c - 2));
        *reinterpret_cast<ushort4*>(&Xs[row * RSH + k]) = z4;
    }
    __syncthreads();

    // MFMA half2 (local tiles 0..8 = global 10..18; gh tail = global >=15)
    for (int idx = 0; idx < H2T; ++idx) {
        int ktl = r9 + idx; if (ktl >= H2T) ktl -= H2T;
        int ktg = 10 + ktl;
        bf16x8 bn[3];
#pragma unroll
        for (int i = 0; i < 3; ++i) bn[i] = b[i];
        if (idx + 1 < H2T) {
            int ktn = r9 + idx + 1; if (ktn >= H2T) ktn -= H2T;
#pragma unroll
            for (int i = 0; i < 3; ++i) {
                int ct = w + 8 * i;
                if (ct < NCT) bn[i] = Wbv[((10 + ktn) * NCT + ct) * 64 + l];
            }
        }
        bf16x8 a[4];
#pragma unroll
        for (int rg = 0; rg < 4; ++rg)
            a[rg] = *reinterpret_cast<const bf16x8*>(
                &Xs[(16 * rg + lrow) * RSH + ktl * 32 + lk * 8]);
        const bool tail = (ktg >= 15);
#pragma unroll
        for (int i = 0; i < 3; ++i) {
            int ct = w + 8 * i;
            if (ct < NCT) {
#pragma unroll
                for (int rg = 0; rg < 4; ++rg)
                    acc[i][rg] = __builtin_amdgcn_mfma_f32_16x16x32_bf16(a[rg], b[i], acc[i][rg], 0, 0, 0);
                if (ct >= 12 && tail) {
#pragma unroll
                    for (int rg = 0; rg < 4; ++rg)
                        acch[rg] = __builtin_amdgcn_mfma_f32_16x16x32_bf16(a[rg], b[i], acch[rg], 0, 0, 0);
                }
            }
        }
#pragma unroll
        for (int i = 0; i < 3; ++i) b[i] = bn[i];
    }
    __syncthreads();   // Xs dead; smem becomes planes

    // epilogue in 4 quarters of 16 rows (rowgroup qt)
    // planesA[r][col 0..303] = combined sums; planesG[r][m 0..99] = gh-only n part
    for (int qt = 0; qt < 4; ++qt) {
#pragma unroll
        for (int i = 0; i < 3; ++i) {
            int ct = w + 8 * i;
            if (ct < NCT) {
                int col = ct * 16 + lrow;
                int rl = lk * 4;
#pragma unroll
                for (int reg = 0; reg < 4; ++reg)
                    planesA[(rl + reg) * PLNA + col] = acc[i][qt][reg];
                if (ct >= 12 && col >= 200 && col < 300) {
#pragma unroll
                    for (int reg = 0; reg < 4; ++reg)
                        planesG[(rl + reg) * PLNG + (col - 200)] = acch[qt][reg];
                }
            }
        }
        __syncthreads();
        for (int idx = tid; idx < 16 * MEMD; idx += NTHR) {
            int r = idx / MEMD, m = idx - r * MEMD;
            size_t node = (size_t)(nbase + qt * 16 + r);
            float p0 = planesA[r * PLNA + m];
            float p1 = planesA[r * PLNA + 100 + m];
            float p2 = planesA[r * PLNA + 200 + m];
            float p3 = planesG[r * PLNG + m];
            float rgv = p0 + b_ih[m] + b_hh[m];
            float zgv = p1 + b_ih[100 + m] + b_hh[100 + m];
            float ghn = p3 + b_hh[200 + m];
            float gin = (p2 - p3) + b_ih[200 + m];
            float rr = fsigmoid(rgv);
            float zz = fsigmoid(zgv);
            float nv = ftanh(gin + rr * ghn);
            out_mem[node * MEMD + m] = (1.f - zz) * nv + zz * memory[node * MEMD + m];
        }
        __syncthreads();
    }
}

extern "C" void kernel_launch(void* const* d_in, const int* in_sizes, int n_in,
                              void* d_out, int out_size, void* d_ws, size_t ws_size,
                              hipStream_t stream) {
    const float* memory = (const float*)d_in[0];
    const float* raw_msg = (const float*)d_in[1];
    const float* time_w = (const float*)d_in[2];
    const float* time_b = (const float*)d_in[3];
    const float* w_ih = (const float*)d_in[4];
    const float* w_hh = (const float*)d_in[5];
    const float* b_ih = (const float*)d_in[6];
    const float* b_hh = (const float*)d_in[7];
    const int* last_update = (const int*)d_in[8];
    const int* src = (const int*)d_in[9];
    const int* dst = (const int*)d_in[10];
    const int* t = (const int*)d_in[11];

    char* ws = (char*)d_ws;
    unsigned long long* keys = (unsigned long long*)ws;       // 1,600,000 B
    int* other = (int*)(ws + 1600000);                        //   800,000 B
    int* ew = (int*)(ws + 2400000);                           //   800,000 B
    float* dtv = (float*)(ws + 3200000);                      //   800,000 B
    unsigned short* Wb = (unsigned short*)(ws + 4000000);     //   369,664 B

    float* out_mem = (float*)d_out;
    float* out_lu = (float*)d_out + (size_t)NN * MEMD;

    hipMemsetAsync(keys, 0, (size_t)NN * 8, stream);
    k_winner<<<(2 * EE + 255) / 256, 256, 0, stream>>>(src, dst, t, keys);
    k_nodeinfo<<<(NN + 255) / 256, 256, 0, stream>>>(keys, src, dst, last_update,
                                                     other, ew, dtv, out_lu);
    k_pack<<<(NKT * NCT * 64 + 255) / 256, 256, 0, stream>>>(w_ih, w_hh, Wb);
    k_fused<<<NN / BM, NTHR, 0, stream>>>(memory, raw_msg, time_w, time_b, b_ih, b_hh,
                                          other, ew, dtv, Wb, out_mem);
}